// Round 3
// baseline (613.656 us; speedup 1.0000x reference)
//
#include <hip/hip_runtime.h>

#define NN 100000
#define NE 3200000
#define HID 64
#define NPB 256                         // nodes per bucket (dl = dst & 255)
#define NB  ((NN + NPB - 1) / NPB)      // 391 buckets
#define CAP 9216                        // raw bucket capacity: mean 8192, +11 sigma
#define MNP 128                         // nodes per window
#define NMW (2 * NB)                    // 782 windows (one k_fuse block each)
#define CAPW 5120                       // padded slots per window: mean 4544, +8.3 sigma
#define CHUNK 4096                      // edges per scatter workgroup
#define NCH ((NE + CHUNK - 1) / CHUNK)  // 782 chunks
#define AP 72                           // f16 agg row pitch in halfs (144 B)
#define BPITCH 136                      // f16 Bt row pitch in halfs (272 B)
#define SRCM 0x1FFFF                    // src mask (17 bits; NN < 2^17)

// dynamic LDS layout for k_fuse (bytes)
#define IMG_B   (CAPW * 8)                          // 40960
#define AGG_B   (MNP * AP * 2)                      // 18432
#define BT_B    (HID * BPITCH * 2)                  // 17408
#define SXL_B   (MNP * 8)                           // 1024
#define FUSE_DYN (IMG_B + AGG_B + BT_B + SXL_B)     // 77824 -> 2 blocks/CU

typedef _Float16 half8 __attribute__((ext_vector_type(8)));
typedef _Float16 h2v   __attribute__((ext_vector_type(2)));
typedef float f32x4 __attribute__((ext_vector_type(4)));

__device__ __forceinline__ unsigned short f2hb(float v) {
    _Float16 h = (_Float16)v;
    unsigned short s;
    __builtin_memcpy(&s, &h, 2);
    return s;
}
__device__ __forceinline__ h2v ash2(unsigned int u) {
    h2v r;
    __builtin_memcpy(&r, &u, 4);
    return r;
}

// -------- init: sx = (0, x) for scatter-time s1 atomics; bucket cursors --------
__global__ __launch_bounds__(512) void k_init(const float* __restrict__ x,
                                              float2* __restrict__ sx,
                                              int* __restrict__ gcur) {
    const int i = blockIdx.x * 512 + threadIdx.x;
    if (i < NN) sx[i] = make_float2(0.f, x[i]);
    if (blockIdx.x == 0 && threadIdx.x < NB) gcur[threadIdx.x] = threadIdx.x * CAP;
}

// -------- scatter: in-LDS counting sort -> bucket-grouped coalesced emission ----
// Also computes s1 via global f32 atomics into sx[d].x (replaces k_s1 kernel).
__global__ __launch_bounds__(256) void k_scatter(const int* __restrict__ src,
                                                 const int* __restrict__ dst,
                                                 const float* __restrict__ ew,
                                                 const float* __restrict__ x,
                                                 float* __restrict__ sxf,
                                                 int* __restrict__ gcur,
                                                 int2* __restrict__ rec,
                                                 unsigned char* __restrict__ dlb) {
    __shared__ int2 lrec[CHUNK];              // 32 KB
    __shared__ unsigned short lb[CHUNK];      // 8 KB  (bucket id per record)
    __shared__ unsigned short sidx[CHUNK];    // 8 KB  (sorted-order -> record idx)
    __shared__ int cnt[NB];                   // counts, then cursor (=excl)
    __shared__ int bme[NB];                   // base - excl
    __shared__ int wt8[8];                    // wave scan partials
    const int tid = threadIdx.x;
    const int lane = tid & 63, wvx = tid >> 6;   // 4 waves
    for (int j = tid; j < NB; j += 256) cnt[j] = 0;
    __syncthreads();
    const long long b0 = (long long)blockIdx.x * CHUNK;
    const int valid = (int)min((long long)CHUNK, (long long)NE - b0);
    #pragma unroll
    for (int k = 0; k < CHUNK / 256; ++k) {
        int idx = k * 256 + tid;
        if (idx < valid) {
            long long e = b0 + idx;
            int d = dst[e];
            int sr = src[e];
            float w = ew[e];
            int b = d >> 8;
            lrec[idx] = make_int2(sr | ((d & 255) << 17), __float_as_int(w));
            lb[idx] = (unsigned short)b;
            atomicAdd(&cnt[b], 1);
            atomicAdd(&sxf[2 * d], w * x[sr]);   // s1 accumulation (fire-and-forget)
        }
    }
    __syncthreads();
    // exclusive scan of 512 slots (NB=391 live) via per-wave shfl scans
    int v0 = (tid < NB) ? cnt[tid] : 0;
    int v1 = (tid + 256 < NB) ? cnt[tid + 256] : 0;
    int i0 = v0, i1 = v1;
    #pragma unroll
    for (int off = 1; off < 64; off <<= 1) {
        int t0 = __shfl_up(i0, off, 64);
        int t1 = __shfl_up(i1, off, 64);
        if (lane >= off) { i0 += t0; i1 += t1; }
    }
    if (lane == 63) { wt8[wvx] = i0; wt8[4 + wvx] = i1; }
    __syncthreads();
    int off0 = 0, off1 = 0;
    #pragma unroll
    for (int j = 0; j < 8; ++j) {
        int wt = wt8[j];
        if (j < wvx) off0 += wt;
        if (j < 4 + wvx) off1 += wt;
    }
    const int excl0 = off0 + i0 - v0;
    const int excl1 = off1 + i1 - v1;
    if (tid < NB) {
        int bb = v0 ? atomicAdd(&gcur[tid], v0) : 0;
        bme[tid] = bb - excl0;
        cnt[tid] = excl0;
    }
    if (tid + 256 < NB) {
        int bb = v1 ? atomicAdd(&gcur[tid + 256], v1) : 0;
        bme[tid + 256] = bb - excl1;
        cnt[tid + 256] = excl1;
    }
    __syncthreads();
    // placement: sorted position per record
    #pragma unroll
    for (int k = 0; k < CHUNK / 256; ++k) {
        int idx = k * 256 + tid;
        if (idx < valid) {
            int sp = atomicAdd(&cnt[lb[idx]], 1);
            sidx[sp] = (unsigned short)idx;
        }
    }
    __syncthreads();
    // emission in bucket order: consecutive lanes -> consecutive addresses per run
    #pragma unroll
    for (int k = 0; k < CHUNK / 256; ++k) {
        int sp = k * 256 + tid;
        if (sp < valid) {
            int idx = sidx[sp];
            int b = lb[idx];
            int2 rc = lrec[idx];
            int go = bme[b] + sp;
            rec[go] = rc;
            dlb[go] = (unsigned char)((rc.x >> 17) & 255);
        }
    }
}

// -------- fused sort2+mega: per-window LDS rec2 image -> stream -> MFMA --------
// One block per 128-node window (= half bucket). No global rec2 round trip.
__global__ __launch_bounds__(512) void k_fuse(
        const int* __restrict__ gcur,
        const int2* __restrict__ rec,
        const unsigned char* __restrict__ dlb,
        const float2* __restrict__ sx,
        const float* __restrict__ W1_rel, const float* __restrict__ W1_root,
        const float* __restrict__ b1,
        const float* __restrict__ W2_rel, const float* __restrict__ b2,
        const float* __restrict__ W2_root,
        const float* __restrict__ W3_rel, const float* __restrict__ W3_root,
        float* __restrict__ p, float* __restrict__ r) {
    extern __shared__ char smem[];
    int4*           img4 = (int4*)smem;                      // CAPW/2 int4, 40960 B
    unsigned short* imgh = (unsigned short*)smem;
    _Float16*       aggh = (_Float16*)(smem + IMG_B);        // 18432 B
    _Float16*       Bt   = (_Float16*)(smem + IMG_B + AGG_B);// 17408 B
    float2*         sxl  = (float2*)(smem + IMG_B + AGG_B + BT_B); // 1024 B
    __shared__ int hist[128];
    __shared__ int exclp[128];
    __shared__ int cur[128];
    __shared__ int ngli[32];                  // 128 u8 group counts
    __shared__ int wt2[2];

    const int tid = threadIdx.x;
    const int lane = tid & 63;
    const int wv = tid >> 6;                  // 0..7
    const int wid = blockIdx.x;
    const int b = wid >> 1, h = wid & 1;      // bucket, half
    const int gi0 = wid * MNP;                // first node of window
    const int f = lane;

    // phase 0: zero img/aggh/hist, stage Bt + sxl
    for (int j = tid; j < CAPW / 2; j += 512) img4[j] = (int4){0, 0, 0, 0};
    for (int j = tid; j < MNP * AP / 2; j += 512) ((int*)aggh)[j] = 0;
    for (int idx = tid; idx < HID * HID; idx += 512) {
        int k = idx >> 6, n = idx & 63;
        Bt[n * BPITCH + k]       = (_Float16)W2_rel[idx];
        Bt[n * BPITCH + HID + k] = (_Float16)W2_root[idx];
    }
    if (tid < MNP) {
        int gi = gi0 + tid;
        sxl[tid] = (gi < NN) ? sx[gi] : make_float2(0.f, 0.f);
    }
    if (tid < 128) hist[tid] = 0;
    const float w1rf = W1_rel[f], w1tf = W1_root[f], b1ff = b1[f];
    __syncthreads();

    // phase 1: histogram of our half from compact dlb stream
    const int beg = b * CAP;
    const int cnt = gcur[b] - beg;
    for (int t = tid; t < cnt; t += 512) {
        int dl = dlb[beg + t];
        if ((dl >> 7) == h) atomicAdd(&hist[dl & 127], 1);
    }
    __syncthreads();

    // phase 2: padded exclusive scan over 128 bins (waves 0-1 live)
    int pc = 0, incl = 0;
    if (tid < 128) { pc = (hist[tid] + 7) & ~7; incl = pc; }
    #pragma unroll
    for (int off = 1; off < 64; off <<= 1) {
        int tt = __shfl_up(incl, off, 64);
        if (lane >= off) incl += tt;
    }
    if (tid < 128 && lane == 63) wt2[wv] = incl;
    __syncthreads();
    if (tid < 128) {
        int e0 = ((tid >= 64) ? wt2[0] : 0) + incl - pc;
        exclp[tid] = e0;
        cur[tid] = e0;
        ((unsigned char*)ngli)[tid] = (unsigned char)(pc >> 3);
    }
    __syncthreads();

    // phase 3: pack our half into LDS image (pair-transposed, pads stay zero)
    for (int t = tid; t < cnt; t += 512) {
        int2 rc = rec[beg + t];
        const int dl = (rc.x >> 17) & 255;
        if ((dl >> 7) != h) continue;
        const float w = __int_as_float(rc.y);
        const float2 v = sx[rc.x & SRCM];
        int gs = atomicAdd(&cur[dl & 127], 1);
        int hb = (gs >> 1) * 8 + (gs & 1);
        imgh[hb]     = f2hb(w * v.x);
        imgh[hb + 2] = f2hb(w * v.y);
        imgh[hb + 4] = f2hb(w);
    }
    __syncthreads();

    // phase 4: branchless pair edge stream from LDS image
    {
        const int soff = __builtin_amdgcn_readfirstlane(exclp[wv * 16]);
        unsigned ua = __builtin_amdgcn_readfirstlane((unsigned)ngli[wv * 4 + 0]);
        unsigned ub = __builtin_amdgcn_readfirstlane((unsigned)ngli[wv * 4 + 1]);
        unsigned uc = __builtin_amdgcn_readfirstlane((unsigned)ngli[wv * 4 + 2]);
        unsigned ud = __builtin_amdgcn_readfirstlane((unsigned)ngli[wv * 4 + 3]);
        unsigned long long clo = (unsigned long long)ua | ((unsigned long long)ub << 32);
        unsigned long long chi = (unsigned long long)uc | ((unsigned long long)ud << 32);
        #define BSUM(u) (((u) & 255u) + (((u) >> 8) & 255u) + (((u) >> 16) & 255u) + ((u) >> 24))
        const int tg = (int)(BSUM(ua) + BSUM(ub) + BSUM(uc) + BSUM(ud));
        #undef BSUM

        const h2v w1r2 = {(_Float16)w1rf, (_Float16)w1rf};
        const h2v w1t2 = {(_Float16)w1tf, (_Float16)w1tf};
        const h2v b1f2 = {(_Float16)b1ff, (_Float16)b1ff};
        const h2v one2 = {(_Float16)1.f, (_Float16)1.f};
        const h2v zero2 = {(_Float16)0.f, (_Float16)0.f};

        float a0 = 0.f, a1 = 0.f, a2 = 0.f, a3 = 0.f;
        int nrow = wv * 16;
        const int rowend = nrow + 16;
        int grem = (int)(clo & 255); clo = (clo >> 8) | (chi << 56); chi >>= 8;
        while (grem == 0 && nrow + 1 < rowend) {
            ++nrow; grem = (int)(clo & 255);
            clo = (clo >> 8) | (chi << 56); chi >>= 8;
        }

        const int4* rp = img4 + (soff >> 1);
        int4 A0, A1, A2, A3, B0, B1, B2, B3;
        if (tg >= 1) { A0 = rp[0]; A1 = rp[1]; A2 = rp[2]; A3 = rp[3]; }
        if (tg >= 2) { B0 = rp[4]; B1 = rp[5]; B2 = rp[6]; B3 = rp[7]; }
        rp += 8;

#define PP(Q, AA) {                                          \
        h2v z_ = ash2((unsigned)(Q).z) * b1f2;               \
        z_ = ash2((unsigned)(Q).y) * w1t2 + z_;              \
        z_ = ash2((unsigned)(Q).x) * w1r2 + z_;              \
        z_ = __builtin_elementwise_max(z_, zero2);           \
        AA = __builtin_amdgcn_fdot2(z_, one2, AA, false); }

#define BNDRY() {                                                        \
        if (--grem == 0) {                                               \
            aggh[nrow * AP + f] = (_Float16)((a0 + a1) + (a2 + a3));     \
            a0 = a1 = a2 = a3 = 0.f;                                     \
            ++nrow; grem = (int)(clo & 255);                             \
            clo = (clo >> 8) | (chi << 56); chi >>= 8;                   \
            while (grem == 0 && nrow + 1 < rowend) {                     \
                ++nrow; grem = (int)(clo & 255);                         \
                clo = (clo >> 8) | (chi << 56); chi >>= 8;               \
            }                                                            \
        } }

        int t = 0;
        while (t + 2 <= tg) {
            PP(A0, a0) PP(A1, a1) PP(A2, a2) PP(A3, a3)
            A0 = rp[0]; A1 = rp[1]; A2 = rp[2]; A3 = rp[3]; rp += 4;
            BNDRY(); ++t;
            PP(B0, a0) PP(B1, a1) PP(B2, a2) PP(B3, a3)
            B0 = rp[0]; B1 = rp[1]; B2 = rp[2]; B3 = rp[3]; rp += 4;
            BNDRY(); ++t;
        }
        if (t < tg) {
            PP(A0, a0) PP(A1, a1) PP(A2, a2) PP(A3, a3)
            BNDRY();
        }
#undef PP
#undef BNDRY
    }
    __syncthreads();

    // phase 5: MFMA layer-2 + fused layer-3 epilogue
    const int m16 = tid & 15;
    const int quad = (tid & 63) >> 4;
    f32x4 acc[4];
    #pragma unroll
    for (int c_ = 0; c_ < 4; ++c_) acc[c_] = (f32x4){0.f, 0.f, 0.f, 0.f};

    const float2 sm = sxl[wv * 16 + m16];

    #pragma unroll
    for (int kt = 0; kt < 4; ++kt) {
        const int kk = kt * 32;
        half8 af;
        if (kt < 2) {
            af = *(const half8*)&aggh[(wv * 16 + m16) * AP + kk + quad * 8];
        } else {
            const int fk0 = (kt - 2) * 32 + quad * 8;
            #pragma unroll
            for (int j = 0; j < 8; ++j) {
                const float wr = W1_rel[fk0 + j], wt = W1_root[fk0 + j], bb = b1[fk0 + j];
                af[j] = (_Float16)fmaxf(0.f, fmaf(sm.x, wr, fmaf(sm.y, wt, bb)));
            }
        }
        #pragma unroll
        for (int ct = 0; ct < 4; ++ct) {
            const half8 bfrag = *(const half8*)&Bt[(ct * 16 + m16) * BPITCH + kk + quad * 8];
            acc[ct] = __builtin_amdgcn_mfma_f32_16x16x32_f16(af, bfrag, acc[ct], 0, 0, 0);
        }
    }

    float b2c[4], w3rc[4], w3tc[4];
    #pragma unroll
    for (int ct = 0; ct < 4; ++ct) {
        const int col = ct * 16 + m16;
        b2c[ct] = b2[col]; w3rc[ct] = W3_rel[col]; w3tc[ct] = W3_root[col];
    }
    float pv[4] = {0.f, 0.f, 0.f, 0.f}, rv[4] = {0.f, 0.f, 0.f, 0.f};
    #pragma unroll
    for (int ct = 0; ct < 4; ++ct) {
        #pragma unroll
        for (int reg = 0; reg < 4; ++reg) {
            const float h2_ = fmaxf(0.f, acc[ct][reg] + b2c[ct]);
            pv[reg] = fmaf(h2_, w3rc[ct], pv[reg]);
            rv[reg] = fmaf(h2_, w3tc[ct], rv[reg]);
        }
    }
    #pragma unroll
    for (int reg = 0; reg < 4; ++reg) {
        #pragma unroll
        for (int msk = 1; msk < 16; msk <<= 1) {
            pv[reg] += __shfl_xor(pv[reg], msk, 64);
            rv[reg] += __shfl_xor(rv[reg], msk, 64);
        }
    }
    if (m16 == 0) {
        #pragma unroll
        for (int reg = 0; reg < 4; ++reg) {
            const int gi = gi0 + wv * 16 + quad * 4 + reg;
            if (gi < NN) { p[gi] = pv[reg]; r[gi] = rv[reg]; }
        }
    }
}

// -------- bucketed output (unsorted rec): out = seg_sum(w * p[src]) + r + b3 --------
__global__ __launch_bounds__(512) void k_out(const int* __restrict__ gcur,
                                             const int2* __restrict__ rec,
                                             const float* __restrict__ pp,
                                             const float* __restrict__ rr,
                                             const float* __restrict__ b3,
                                             float* __restrict__ out) {
    __shared__ float loc[NPB];
    if (threadIdx.x < NPB) loc[threadIdx.x] = 0.f;
    __syncthreads();
    const int b = blockIdx.x;
    const int beg = b * CAP, cnt = gcur[b] - beg;
    for (int t = threadIdx.x; t < cnt; t += 512) {
        int2 rc = rec[beg + t];
        atomicAdd(&loc[rc.x >> 17], __int_as_float(rc.y) * pp[rc.x & SRCM]);
    }
    __syncthreads();
    int i = b * NPB + threadIdx.x;
    if (threadIdx.x < NPB && i < NN) out[i] = loc[threadIdx.x] + rr[i] + b3[0];
}

extern "C" void kernel_launch(void* const* d_in, const int* in_sizes, int n_in,
                              void* d_out, int out_size, void* d_ws, size_t ws_size,
                              hipStream_t stream) {
    const float* x       = (const float*)d_in[0];
    const int*   ei      = (const int*)  d_in[1];
    const float* ew      = (const float*)d_in[2];
    const float* W1_rel  = (const float*)d_in[3];
    const float* b1      = (const float*)d_in[4];
    const float* W1_root = (const float*)d_in[5];
    const float* W2_rel  = (const float*)d_in[6];
    const float* b2      = (const float*)d_in[7];
    const float* W2_root = (const float*)d_in[8];
    const float* W3_rel  = (const float*)d_in[9];
    const float* b3      = (const float*)d_in[10];
    const float* W3_root = (const float*)d_in[11];

    const int* src = ei;
    const int* dst = ei + NE;

    // workspace layout (~34 MB of the ~268 MB workspace)
    const size_t REC_SLOTS = (size_t)NB * CAP;            // 3.60M slots, 28.8 MB
    int2*          rec   = (int2*)d_ws;
    float2*        sx    = (float2*)(rec + REC_SLOTS);    // 800 KB
    float*         p     = (float*)(sx + NN);             // 400 KB
    float*         r     = p + NN;                        // 400 KB
    int*           gcur  = (int*)(r + NN);                // NB*4
    unsigned char* dlb   = (unsigned char*)(gcur + NB);   // NB*CAP = 3.6 MB

    k_init<<<(NN + 511) / 512, 512, 0, stream>>>(x, sx, gcur);
    k_scatter<<<NCH, 256, 0, stream>>>(src, dst, ew, x, (float*)sx, gcur, rec, dlb);
    k_fuse<<<NMW, 512, FUSE_DYN, stream>>>(gcur, rec, dlb, sx,
                                           W1_rel, W1_root, b1,
                                           W2_rel, b2, W2_root,
                                           W3_rel, W3_root, p, r);
    k_out<<<NB, 512, 0, stream>>>(gcur, rec, p, r, b3, (float*)d_out);
}

// Round 4
// 384.030 us; speedup vs baseline: 1.5979x; 1.5979x over previous
//
#include <hip/hip_runtime.h>

#define NN 100000
#define NE 3200000
#define HID 64
#define NPB 256                         // nodes per bucket (dl = dst & 255)
#define NB  ((NN + NPB - 1) / NPB)      // 391 buckets
#define NNP (NB * NPB)                  // 100096 padded node slots
#define CAP 9216                        // raw bucket capacity: mean 8192, +11 sigma
#define MNP 128                         // nodes per window
#define NMW (2 * NB)                    // 782 windows
#define CAPW 5120                       // padded slots per window: mean ~4544, +8.7 sigma
#define CHUNK 4096                      // edges per scatter workgroup
#define NCH ((NE + CHUNK - 1) / CHUNK)  // 782 chunks
#define AP 72                           // f16 agg row pitch in halfs (144 B)
#define BPITCH 136                      // f16 Bt row pitch in halfs (272 B)
#define SRCM 0x1FFFF                    // src mask (17 bits; NN < 2^17)

typedef _Float16 half8 __attribute__((ext_vector_type(8)));
typedef _Float16 h2v   __attribute__((ext_vector_type(2)));
typedef float f32x4 __attribute__((ext_vector_type(4)));

__device__ __forceinline__ unsigned short f2hb(float v) {
    _Float16 h = (_Float16)v;
    unsigned short s;
    __builtin_memcpy(&s, &h, 2);
    return s;
}
__device__ __forceinline__ h2v ash2(unsigned int u) {
    h2v r;
    __builtin_memcpy(&r, &u, 4);
    return r;
}

// -------- init: sx = (0, x) for scatter-time s1 atomics; bucket cursors --------
__global__ __launch_bounds__(512) void k_init(const float* __restrict__ x,
                                              float2* __restrict__ sx,
                                              int* __restrict__ gcur) {
    const int i = blockIdx.x * 512 + threadIdx.x;
    if (i < NN) sx[i] = make_float2(0.f, x[i]);
    if (blockIdx.x == 0 && threadIdx.x < NB) gcur[threadIdx.x] = threadIdx.x * CAP;
}

// -------- scatter: in-LDS counting sort -> bucket-grouped coalesced emission ----
// Also computes s1 via global f32 atomics into sx[d].x (replaces k_s1 kernel).
__global__ __launch_bounds__(256) void k_scatter(const int* __restrict__ src,
                                                 const int* __restrict__ dst,
                                                 const float* __restrict__ ew,
                                                 const float* __restrict__ x,
                                                 float* __restrict__ sxf,
                                                 int* __restrict__ gcur,
                                                 int2* __restrict__ rec,
                                                 unsigned char* __restrict__ dlb) {
    __shared__ int2 lrec[CHUNK];              // 32 KB
    __shared__ unsigned short lb[CHUNK];      // 8 KB  (bucket id per record)
    __shared__ unsigned short sidx[CHUNK];    // 8 KB  (sorted-order -> record idx)
    __shared__ int cnt[NB];                   // counts, then cursor (=excl)
    __shared__ int bme[NB];                   // base - excl
    __shared__ int wt8[8];                    // wave scan partials
    const int tid = threadIdx.x;
    const int lane = tid & 63, wvx = tid >> 6;   // 4 waves
    for (int j = tid; j < NB; j += 256) cnt[j] = 0;
    __syncthreads();
    const long long b0 = (long long)blockIdx.x * CHUNK;
    const int valid = (int)min((long long)CHUNK, (long long)NE - b0);
    #pragma unroll
    for (int k = 0; k < CHUNK / 256; ++k) {
        int idx = k * 256 + tid;
        if (idx < valid) {
            long long e = b0 + idx;
            int d = dst[e];
            int sr = src[e];
            float w = ew[e];
            int b = d >> 8;
            lrec[idx] = make_int2(sr | ((d & 255) << 17), __float_as_int(w));
            lb[idx] = (unsigned short)b;
            atomicAdd(&cnt[b], 1);
            atomicAdd(&sxf[2 * d], w * x[sr]);   // s1 accumulation (fire-and-forget)
        }
    }
    __syncthreads();
    // exclusive scan of 512 slots (NB=391 live) via per-wave shfl scans
    int v0 = (tid < NB) ? cnt[tid] : 0;
    int v1 = (tid + 256 < NB) ? cnt[tid + 256] : 0;
    int i0 = v0, i1 = v1;
    #pragma unroll
    for (int off = 1; off < 64; off <<= 1) {
        int t0 = __shfl_up(i0, off, 64);
        int t1 = __shfl_up(i1, off, 64);
        if (lane >= off) { i0 += t0; i1 += t1; }
    }
    if (lane == 63) { wt8[wvx] = i0; wt8[4 + wvx] = i1; }
    __syncthreads();
    int off0 = 0, off1 = 0;
    #pragma unroll
    for (int j = 0; j < 8; ++j) {
        int wt = wt8[j];
        if (j < wvx) off0 += wt;
        if (j < 4 + wvx) off1 += wt;
    }
    const int excl0 = off0 + i0 - v0;
    const int excl1 = off1 + i1 - v1;
    if (tid < NB) {
        int bb = v0 ? atomicAdd(&gcur[tid], v0) : 0;
        bme[tid] = bb - excl0;
        cnt[tid] = excl0;
    }
    if (tid + 256 < NB) {
        int bb = v1 ? atomicAdd(&gcur[tid + 256], v1) : 0;
        bme[tid + 256] = bb - excl1;
        cnt[tid + 256] = excl1;
    }
    __syncthreads();
    // placement: sorted position per record
    #pragma unroll
    for (int k = 0; k < CHUNK / 256; ++k) {
        int idx = k * 256 + tid;
        if (idx < valid) {
            int sp = atomicAdd(&cnt[lb[idx]], 1);
            sidx[sp] = (unsigned short)idx;
        }
    }
    __syncthreads();
    // emission in bucket order: consecutive lanes -> consecutive addresses per run
    #pragma unroll
    for (int k = 0; k < CHUNK / 256; ++k) {
        int sp = k * 256 + tid;
        if (sp < valid) {
            int idx = sidx[sp];
            int b = lb[idx];
            int2 rc = lrec[idx];
            int go = bme[b] + sp;
            rec[go] = rc;
            dlb[go] = (unsigned char)((rc.x >> 17) & 255);
        }
    }
}

// -------- pack: per-window LDS rec2 image (scattered u16 -> LDS), coalesced dump ----
// One block per 128-node window (half bucket). Replaces sort2's scattered global
// u16 stores (72.8 MB measured) with a linear 40 KB int4 dump (32 MB exact).
__global__ __launch_bounds__(512) void k_pack(const int* __restrict__ gcur,
                                              const int2* __restrict__ rec,
                                              const unsigned char* __restrict__ dlb,
                                              const float2* __restrict__ sx,
                                              int4* __restrict__ rec2q,
                                              int* __restrict__ noff,
                                              unsigned char* __restrict__ ngrp) {
    __shared__ int4 img4[CAPW / 2];           // 40960 B
    __shared__ int hist[128];
    __shared__ int exclp[128];
    __shared__ int cur[128];
    __shared__ int wt2[2];
    unsigned short* imgh = (unsigned short*)img4;
    const int tid = threadIdx.x;
    const int lane = tid & 63, wv = tid >> 6;
    const int wid = blockIdx.x;
    const int b = wid >> 1, h = wid & 1;
    for (int j = tid; j < CAPW / 2; j += 512) img4[j] = (int4){0, 0, 0, 0};
    if (tid < 128) hist[tid] = 0;
    __syncthreads();
    const int beg = b * CAP;
    const int cnt = gcur[b] - beg;
    // histogram of our half from compact dlb stream (uchar4 loads)
    {
        const uchar4* d4 = (const uchar4*)(dlb + beg);
        const int n4 = cnt >> 2;
        for (int t = tid; t < n4; t += 512) {
            uchar4 q = d4[t];
            if ((q.x >> 7) == h) atomicAdd(&hist[q.x & 127], 1);
            if ((q.y >> 7) == h) atomicAdd(&hist[q.y & 127], 1);
            if ((q.z >> 7) == h) atomicAdd(&hist[q.z & 127], 1);
            if ((q.w >> 7) == h) atomicAdd(&hist[q.w & 127], 1);
        }
        for (int t = (n4 << 2) + tid; t < cnt; t += 512) {
            int dl = dlb[beg + t];
            if ((dl >> 7) == h) atomicAdd(&hist[dl & 127], 1);
        }
    }
    __syncthreads();
    // padded exclusive scan over 128 bins (waves 0-1 live)
    int pc = 0, incl = 0;
    if (tid < 128) { pc = (hist[tid] + 7) & ~7; incl = pc; }
    #pragma unroll
    for (int off = 1; off < 64; off <<= 1) {
        int tt = __shfl_up(incl, off, 64);
        if (lane >= off) incl += tt;
    }
    if (tid < 128 && lane == 63) wt2[wv] = incl;
    __syncthreads();
    if (tid < 128) {
        int e0 = ((tid >= 64) ? wt2[0] : 0) + incl - pc;
        exclp[tid] = e0;
        cur[tid] = e0;
        const int node = wid * MNP + tid;     // node < NNP always
        noff[node] = wid * CAPW + e0;         // absolute slot offset (mult of 8)
        ngrp[node] = (unsigned char)(pc >> 3);
    }
    __syncthreads();
    // pass2: stream rec (int4 = 2 records), gather sx, scatter into LDS image
#define PREC(RX, RY) {                                                  \
        const int dl_ = ((RX) >> 17) & 255;                             \
        if ((dl_ >> 7) == h) {                                          \
            const float w_ = __int_as_float(RY);                        \
            const float2 v_ = sx[(RX) & SRCM];                          \
            int gs_ = atomicAdd(&cur[dl_ & 127], 1);                    \
            int hb_ = (gs_ >> 1) * 8 + (gs_ & 1);                       \
            imgh[hb_]     = f2hb(w_ * v_.x);                            \
            imgh[hb_ + 2] = f2hb(w_ * v_.y);                            \
            imgh[hb_ + 4] = f2hb(w_);                                   \
        } }
    {
        const int4* r4 = (const int4*)(rec + beg);
        const int n2 = cnt >> 1;
        for (int t = tid; t < n2; t += 512) {
            int4 q = r4[t];
            PREC(q.x, q.y)
            PREC(q.z, q.w)
        }
        for (int t = (n2 << 1) + tid; t < cnt; t += 512) {
            int2 rc = rec[beg + t];
            PREC(rc.x, rc.y)
        }
    }
#undef PREC
    __syncthreads();
    // coalesced dump: 40960 B per window
    int4* d4 = rec2q + (size_t)wid * (CAPW / 2);
    for (int j = tid; j < CAPW / 2; j += 512) d4[j] = img4[j];
}

// -------- mega: branchless pair-transposed global streaming + MFMA (R2-proven) ----
__global__ __launch_bounds__(512) void k_mega(
        const int* __restrict__ noff, const unsigned char* __restrict__ ngrp,
        const char* __restrict__ rec2b, const float2* __restrict__ sx,
        const float* __restrict__ W1_rel, const float* __restrict__ W1_root,
        const float* __restrict__ b1,
        const float* __restrict__ W2_rel, const float* __restrict__ b2,
        const float* __restrict__ W2_root,
        const float* __restrict__ W3_rel, const float* __restrict__ W3_root,
        float* __restrict__ p, float* __restrict__ r) {
    __shared__ _Float16 aggh[MNP * AP];       // 18432 B
    __shared__ _Float16 Bt[HID * BPITCH];     // 17408 B
    __shared__ float2 sxl[MNP];               // 1024 B -> 36.9 KB
    const int tid = threadIdx.x;
    const int f = tid & 63;
    const int wv = tid >> 6;                  // 0..7
    const int gi0 = blockIdx.x * MNP;

    for (int j = tid; j < MNP * AP / 2; j += 512) ((int*)aggh)[j] = 0;
    for (int idx = tid; idx < HID * HID; idx += 512) {
        int k = idx >> 6, n = idx & 63;
        Bt[n * BPITCH + k]       = (_Float16)W2_rel[idx];
        Bt[n * BPITCH + HID + k] = (_Float16)W2_root[idx];
    }
    if (tid < MNP) {
        int gi = gi0 + tid;
        sxl[tid] = (gi < NN) ? sx[gi] : make_float2(0.f, 0.f);
    }
    const float w1rf = W1_rel[f], w1tf = W1_root[f], b1ff = b1[f];
    __syncthreads();

    {
        const int first = gi0 + wv * 16;
        int soff = __builtin_amdgcn_readfirstlane(noff[first]);
        const int4 gvv = *(const int4*)(ngrp + first);
        unsigned ua = __builtin_amdgcn_readfirstlane((unsigned)gvv.x);
        unsigned ub = __builtin_amdgcn_readfirstlane((unsigned)gvv.y);
        unsigned uc = __builtin_amdgcn_readfirstlane((unsigned)gvv.z);
        unsigned ud = __builtin_amdgcn_readfirstlane((unsigned)gvv.w);
        unsigned long long clo = (unsigned long long)ua | ((unsigned long long)ub << 32);
        unsigned long long chi = (unsigned long long)uc | ((unsigned long long)ud << 32);
        #define BSUM(u) (((u) & 255u) + (((u) >> 8) & 255u) + (((u) >> 16) & 255u) + ((u) >> 24))
        const int tg = (int)(BSUM(ua) + BSUM(ub) + BSUM(uc) + BSUM(ud));
        #undef BSUM

        const h2v w1r2 = {(_Float16)w1rf, (_Float16)w1rf};
        const h2v w1t2 = {(_Float16)w1tf, (_Float16)w1tf};
        const h2v b1f2 = {(_Float16)b1ff, (_Float16)b1ff};
        const h2v one2 = {(_Float16)1.f, (_Float16)1.f};
        const h2v zero2 = {(_Float16)0.f, (_Float16)0.f};

        float a0 = 0.f, a1 = 0.f, a2 = 0.f, a3 = 0.f;
        int nrow = wv * 16;
        const int rowend = nrow + 16;
        int grem = (int)(clo & 255); clo = (clo >> 8) | (chi << 56); chi >>= 8;
        while (grem == 0 && nrow + 1 < rowend) {
            ++nrow; grem = (int)(clo & 255);
            clo = (clo >> 8) | (chi << 56); chi >>= 8;
        }

        const int4* rp = (const int4*)rec2b + (soff >> 1);
        int4 A0, A1, A2, A3, B0, B1, B2, B3;
        if (tg >= 1) { A0 = rp[0]; A1 = rp[1]; A2 = rp[2]; A3 = rp[3]; }
        if (tg >= 2) { B0 = rp[4]; B1 = rp[5]; B2 = rp[6]; B3 = rp[7]; }
        rp += 8;

#define PP(Q, AA) {                                          \
        h2v z_ = ash2((unsigned)(Q).z) * b1f2;               \
        z_ = ash2((unsigned)(Q).y) * w1t2 + z_;              \
        z_ = ash2((unsigned)(Q).x) * w1r2 + z_;              \
        z_ = __builtin_elementwise_max(z_, zero2);           \
        AA = __builtin_amdgcn_fdot2(z_, one2, AA, false); }

#define BNDRY() {                                                        \
        if (--grem == 0) {                                               \
            aggh[nrow * AP + f] = (_Float16)((a0 + a1) + (a2 + a3));     \
            a0 = a1 = a2 = a3 = 0.f;                                     \
            ++nrow; grem = (int)(clo & 255);                             \
            clo = (clo >> 8) | (chi << 56); chi >>= 8;                   \
            while (grem == 0 && nrow + 1 < rowend) {                     \
                ++nrow; grem = (int)(clo & 255);                         \
                clo = (clo >> 8) | (chi << 56); chi >>= 8;               \
            }                                                            \
        } }

        int t = 0;
        while (t + 2 <= tg) {
            PP(A0, a0) PP(A1, a1) PP(A2, a2) PP(A3, a3)
            A0 = rp[0]; A1 = rp[1]; A2 = rp[2]; A3 = rp[3]; rp += 4;
            BNDRY(); ++t;
            PP(B0, a0) PP(B1, a1) PP(B2, a2) PP(B3, a3)
            B0 = rp[0]; B1 = rp[1]; B2 = rp[2]; B3 = rp[3]; rp += 4;
            BNDRY(); ++t;
        }
        if (t < tg) {
            PP(A0, a0) PP(A1, a1) PP(A2, a2) PP(A3, a3)
            BNDRY();
        }
#undef PP
#undef BNDRY
    }
    __syncthreads();

    const int m16 = tid & 15;
    const int quad = (tid & 63) >> 4;
    f32x4 acc[4];
    #pragma unroll
    for (int c_ = 0; c_ < 4; ++c_) acc[c_] = (f32x4){0.f, 0.f, 0.f, 0.f};

    const float2 sm = sxl[wv * 16 + m16];

    #pragma unroll
    for (int kt = 0; kt < 4; ++kt) {
        const int kk = kt * 32;
        half8 af;
        if (kt < 2) {
            af = *(const half8*)&aggh[(wv * 16 + m16) * AP + kk + quad * 8];
        } else {
            const int fk0 = (kt - 2) * 32 + quad * 8;
            #pragma unroll
            for (int j = 0; j < 8; ++j) {
                const float wr = W1_rel[fk0 + j], wt = W1_root[fk0 + j], bb = b1[fk0 + j];
                af[j] = (_Float16)fmaxf(0.f, fmaf(sm.x, wr, fmaf(sm.y, wt, bb)));
            }
        }
        #pragma unroll
        for (int ct = 0; ct < 4; ++ct) {
            const half8 bfrag = *(const half8*)&Bt[(ct * 16 + m16) * BPITCH + kk + quad * 8];
            acc[ct] = __builtin_amdgcn_mfma_f32_16x16x32_f16(af, bfrag, acc[ct], 0, 0, 0);
        }
    }

    float b2c[4], w3rc[4], w3tc[4];
    #pragma unroll
    for (int ct = 0; ct < 4; ++ct) {
        const int col = ct * 16 + m16;
        b2c[ct] = b2[col]; w3rc[ct] = W3_rel[col]; w3tc[ct] = W3_root[col];
    }
    float pv[4] = {0.f, 0.f, 0.f, 0.f}, rv[4] = {0.f, 0.f, 0.f, 0.f};
    #pragma unroll
    for (int ct = 0; ct < 4; ++ct) {
        #pragma unroll
        for (int reg = 0; reg < 4; ++reg) {
            const float h2_ = fmaxf(0.f, acc[ct][reg] + b2c[ct]);
            pv[reg] = fmaf(h2_, w3rc[ct], pv[reg]);
            rv[reg] = fmaf(h2_, w3tc[ct], rv[reg]);
        }
    }
    #pragma unroll
    for (int reg = 0; reg < 4; ++reg) {
        #pragma unroll
        for (int msk = 1; msk < 16; msk <<= 1) {
            pv[reg] += __shfl_xor(pv[reg], msk, 64);
            rv[reg] += __shfl_xor(rv[reg], msk, 64);
        }
    }
    if (m16 == 0) {
        #pragma unroll
        for (int reg = 0; reg < 4; ++reg) {
            const int gi = gi0 + wv * 16 + quad * 4 + reg;
            if (gi < NN) { p[gi] = pv[reg]; r[gi] = rv[reg]; }
        }
    }
}

// -------- bucketed output (unsorted rec): out = seg_sum(w * p[src]) + r + b3 --------
__global__ __launch_bounds__(512) void k_out(const int* __restrict__ gcur,
                                             const int2* __restrict__ rec,
                                             const float* __restrict__ pp,
                                             const float* __restrict__ rr,
                                             const float* __restrict__ b3,
                                             float* __restrict__ out) {
    __shared__ float loc[NPB];
    if (threadIdx.x < NPB) loc[threadIdx.x] = 0.f;
    __syncthreads();
    const int b = blockIdx.x;
    const int beg = b * CAP, cnt = gcur[b] - beg;
    for (int t = threadIdx.x; t < cnt; t += 512) {
        int2 rc = rec[beg + t];
        atomicAdd(&loc[rc.x >> 17], __int_as_float(rc.y) * pp[rc.x & SRCM]);
    }
    __syncthreads();
    int i = b * NPB + threadIdx.x;
    if (threadIdx.x < NPB && i < NN) out[i] = loc[threadIdx.x] + rr[i] + b3[0];
}

extern "C" void kernel_launch(void* const* d_in, const int* in_sizes, int n_in,
                              void* d_out, int out_size, void* d_ws, size_t ws_size,
                              hipStream_t stream) {
    const float* x       = (const float*)d_in[0];
    const int*   ei      = (const int*)  d_in[1];
    const float* ew      = (const float*)d_in[2];
    const float* W1_rel  = (const float*)d_in[3];
    const float* b1      = (const float*)d_in[4];
    const float* W1_root = (const float*)d_in[5];
    const float* W2_rel  = (const float*)d_in[6];
    const float* b2      = (const float*)d_in[7];
    const float* W2_root = (const float*)d_in[8];
    const float* W3_rel  = (const float*)d_in[9];
    const float* b3      = (const float*)d_in[10];
    const float* W3_root = (const float*)d_in[11];

    const int* src = ei;
    const int* dst = ei + NE;

    // workspace layout (~67 MB of the ~268 MB workspace)
    const size_t REC_SLOTS = (size_t)NB * CAP;            // 3.60M slots, 28.8 MB
    int2*          rec   = (int2*)d_ws;
    float2*        sx    = (float2*)(rec + REC_SLOTS);    // 800 KB
    float*         p     = (float*)(sx + NN);             // 400 KB
    float*         r     = p + NN;                        // 400 KB
    int*           noff  = (int*)(r + NN);                // NNP*4
    unsigned char* ngrp  = (unsigned char*)(noff + NNP);  // NNP (16B-aligned)
    int*           gcur  = (int*)(ngrp + NNP);            // NB*4
    unsigned char* dlb   = (unsigned char*)(gcur + NB);   // NB*CAP = 3.6 MB
    char*          tail  = (char*)(dlb + REC_SLOTS);
    size_t         off   = ((size_t)(tail - (char*)d_ws) + 15) & ~(size_t)15;
    char*          rec2  = (char*)d_ws + off;             // NMW*CAPW*8 + 256 slack = 32.0 MB

    k_init<<<(NN + 511) / 512, 512, 0, stream>>>(x, sx, gcur);
    k_scatter<<<NCH, 256, 0, stream>>>(src, dst, ew, x, (float*)sx, gcur, rec, dlb);
    k_pack<<<NMW, 512, 0, stream>>>(gcur, rec, dlb, sx, (int4*)rec2, noff, ngrp);
    k_mega<<<NMW, 512, 0, stream>>>(noff, ngrp, rec2, sx,
                                    W1_rel, W1_root, b1,
                                    W2_rel, b2, W2_root,
                                    W3_rel, W3_root, p, r);
    k_out<<<NB, 512, 0, stream>>>(gcur, rec, p, r, b3, (float*)d_out);
}

// Round 5
// 259.625 us; speedup vs baseline: 2.3636x; 1.4792x over previous
//
#include <hip/hip_runtime.h>

#define NN 100000
#define NE 3200000
#define HID 64
#define NPB 256                         // nodes per bucket (dl = dst & 255)
#define NB  ((NN + NPB - 1) / NPB)      // 391 buckets
#define NNP (NB * NPB)                  // 100096 padded node slots
#define CAP 9216                        // raw bucket capacity: mean 8192, +11 sigma
#define MNP 128                         // nodes per window
#define NMW (2 * NB)                    // 782 windows
#define CAPW 5120                       // padded slots per window: mean ~4544, +8.7 sigma
#define CHUNK 4096                      // edges per scatter workgroup
#define NCH ((NE + CHUNK - 1) / CHUNK)  // 782 chunks
#define AP 72                           // f16 agg row pitch in halfs (144 B)
#define BPITCH 136                      // f16 Bt row pitch in halfs (272 B)
#define SRCM 0x1FFFF                    // src mask (17 bits; NN < 2^17)

typedef _Float16 half8 __attribute__((ext_vector_type(8)));
typedef _Float16 h2v   __attribute__((ext_vector_type(2)));
typedef float f32x4 __attribute__((ext_vector_type(4)));

__device__ __forceinline__ unsigned short f2hb(float v) {
    _Float16 h = (_Float16)v;
    unsigned short s;
    __builtin_memcpy(&s, &h, 2);
    return s;
}
__device__ __forceinline__ h2v ash2(unsigned int u) {
    h2v r;
    __builtin_memcpy(&r, &u, 4);
    return r;
}

// -------- init fixed-capacity bucket cursors --------
__global__ __launch_bounds__(512) void k_init(int* __restrict__ gcur) {
    if (threadIdx.x < NB) gcur[threadIdx.x] = threadIdx.x * CAP;
}

// -------- scatter: in-LDS counting sort -> bucket-grouped coalesced emission ----
// (R2-proven form: NO global atomics — the R4 s1-atomics cost 140 MB of writes.)
__global__ __launch_bounds__(256) void k_scatter(const int* __restrict__ src,
                                                 const int* __restrict__ dst,
                                                 const float* __restrict__ ew,
                                                 int* __restrict__ gcur,
                                                 int2* __restrict__ rec,
                                                 unsigned char* __restrict__ dlb) {
    __shared__ int2 lrec[CHUNK];              // 32 KB
    __shared__ unsigned short lb[CHUNK];      // 8 KB  (bucket id per record)
    __shared__ unsigned short sidx[CHUNK];    // 8 KB  (sorted-order -> record idx)
    __shared__ int cnt[NB];                   // counts, then cursor (=excl)
    __shared__ int bme[NB];                   // base - excl
    __shared__ int wt8[8];                    // wave scan partials
    const int tid = threadIdx.x;
    const int lane = tid & 63, wvx = tid >> 6;   // 4 waves
    for (int j = tid; j < NB; j += 256) cnt[j] = 0;
    __syncthreads();
    const long long b0 = (long long)blockIdx.x * CHUNK;
    const int valid = (int)min((long long)CHUNK, (long long)NE - b0);
    #pragma unroll
    for (int k = 0; k < CHUNK / 256; ++k) {
        int idx = k * 256 + tid;
        if (idx < valid) {
            long long e = b0 + idx;
            int d = dst[e];
            int b = d >> 8;
            lrec[idx] = make_int2(src[e] | ((d & 255) << 17), __float_as_int(ew[e]));
            lb[idx] = (unsigned short)b;
            atomicAdd(&cnt[b], 1);
        }
    }
    __syncthreads();
    // exclusive scan of 512 slots (NB=391 live) via per-wave shfl scans
    int v0 = (tid < NB) ? cnt[tid] : 0;
    int v1 = (tid + 256 < NB) ? cnt[tid + 256] : 0;
    int i0 = v0, i1 = v1;
    #pragma unroll
    for (int off = 1; off < 64; off <<= 1) {
        int t0 = __shfl_up(i0, off, 64);
        int t1 = __shfl_up(i1, off, 64);
        if (lane >= off) { i0 += t0; i1 += t1; }
    }
    if (lane == 63) { wt8[wvx] = i0; wt8[4 + wvx] = i1; }
    __syncthreads();
    int off0 = 0, off1 = 0;
    #pragma unroll
    for (int j = 0; j < 8; ++j) {
        int wt = wt8[j];
        if (j < wvx) off0 += wt;
        if (j < 4 + wvx) off1 += wt;
    }
    const int excl0 = off0 + i0 - v0;
    const int excl1 = off1 + i1 - v1;
    if (tid < NB) {
        int bb = v0 ? atomicAdd(&gcur[tid], v0) : 0;
        bme[tid] = bb - excl0;
        cnt[tid] = excl0;
    }
    if (tid + 256 < NB) {
        int bb = v1 ? atomicAdd(&gcur[tid + 256], v1) : 0;
        bme[tid + 256] = bb - excl1;
        cnt[tid + 256] = excl1;
    }
    __syncthreads();
    // placement: sorted position per record
    #pragma unroll
    for (int k = 0; k < CHUNK / 256; ++k) {
        int idx = k * 256 + tid;
        if (idx < valid) {
            int sp = atomicAdd(&cnt[lb[idx]], 1);
            sidx[sp] = (unsigned short)idx;
        }
    }
    __syncthreads();
    // emission in bucket order: consecutive lanes -> consecutive addresses per run
    #pragma unroll
    for (int k = 0; k < CHUNK / 256; ++k) {
        int sp = k * 256 + tid;
        if (sp < valid) {
            int idx = sidx[sp];
            int b = lb[idx];
            int2 rc = lrec[idx];
            int go = bme[b] + sp;
            rec[go] = rc;
            dlb[go] = (unsigned char)((rc.x >> 17) & 255);
        }
    }
}

// -------- bucketed s1: sx[i] = (s1[i], x[i])  (R2-proven LDS-atomic form) --------
__global__ __launch_bounds__(512) void k_s1(const int* __restrict__ gcur,
                                            const int2* __restrict__ rec,
                                            const float* __restrict__ x,
                                            float2* __restrict__ sx) {
    __shared__ float loc[NPB];
    if (threadIdx.x < NPB) loc[threadIdx.x] = 0.f;
    __syncthreads();
    const int b = blockIdx.x;
    const int beg = b * CAP, cnt = gcur[b] - beg;
    for (int t = threadIdx.x; t < cnt; t += 512) {
        int2 rc = rec[beg + t];
        atomicAdd(&loc[rc.x >> 17], __int_as_float(rc.y) * x[rc.x & SRCM]);
    }
    __syncthreads();
    int i = b * NPB + threadIdx.x;
    if (threadIdx.x < NPB && i < NN) sx[i] = make_float2(loc[threadIdx.x], x[i]);
}

// -------- pack: per-window LDS rec2 image (scattered u16 -> LDS), coalesced dump ----
__global__ __launch_bounds__(512) void k_pack(const int* __restrict__ gcur,
                                              const int2* __restrict__ rec,
                                              const unsigned char* __restrict__ dlb,
                                              const float2* __restrict__ sx,
                                              int4* __restrict__ rec2q,
                                              int* __restrict__ noff,
                                              unsigned char* __restrict__ ngrp) {
    __shared__ int4 img4[CAPW / 2];           // 40960 B
    __shared__ int hist[128];
    __shared__ int exclp[128];
    __shared__ int cur[128];
    __shared__ int wt2[2];
    unsigned short* imgh = (unsigned short*)img4;
    const int tid = threadIdx.x;
    const int lane = tid & 63, wv = tid >> 6;
    const int wid = blockIdx.x;
    const int b = wid >> 1, h = wid & 1;
    for (int j = tid; j < CAPW / 2; j += 512) img4[j] = (int4){0, 0, 0, 0};
    if (tid < 128) hist[tid] = 0;
    __syncthreads();
    const int beg = b * CAP;
    const int cnt = gcur[b] - beg;
    // histogram of our half from compact dlb stream (uchar4 loads)
    {
        const uchar4* d4 = (const uchar4*)(dlb + beg);
        const int n4 = cnt >> 2;
        for (int t = tid; t < n4; t += 512) {
            uchar4 q = d4[t];
            if ((q.x >> 7) == h) atomicAdd(&hist[q.x & 127], 1);
            if ((q.y >> 7) == h) atomicAdd(&hist[q.y & 127], 1);
            if ((q.z >> 7) == h) atomicAdd(&hist[q.z & 127], 1);
            if ((q.w >> 7) == h) atomicAdd(&hist[q.w & 127], 1);
        }
        for (int t = (n4 << 2) + tid; t < cnt; t += 512) {
            int dl = dlb[beg + t];
            if ((dl >> 7) == h) atomicAdd(&hist[dl & 127], 1);
        }
    }
    __syncthreads();
    // padded exclusive scan over 128 bins (waves 0-1 live)
    int pc = 0, incl = 0;
    if (tid < 128) { pc = (hist[tid] + 7) & ~7; incl = pc; }
    #pragma unroll
    for (int off = 1; off < 64; off <<= 1) {
        int tt = __shfl_up(incl, off, 64);
        if (lane >= off) incl += tt;
    }
    if (tid < 128 && lane == 63) wt2[wv] = incl;
    __syncthreads();
    if (tid < 128) {
        int e0 = ((tid >= 64) ? wt2[0] : 0) + incl - pc;
        exclp[tid] = e0;
        cur[tid] = e0;
        const int node = wid * MNP + tid;
        noff[node] = wid * CAPW + e0;         // absolute slot offset (mult of 8)
        ngrp[node] = (unsigned char)(pc >> 3);
    }
    __syncthreads();
    // pass2: stream rec (int4 = 2 records), gather sx, scatter into LDS image
#define PREC(RX, RY) {                                                  \
        const int dl_ = ((RX) >> 17) & 255;                             \
        if ((dl_ >> 7) == h) {                                          \
            const float w_ = __int_as_float(RY);                        \
            const float2 v_ = sx[(RX) & SRCM];                          \
            int gs_ = atomicAdd(&cur[dl_ & 127], 1);                    \
            int hb_ = (gs_ >> 1) * 8 + (gs_ & 1);                       \
            imgh[hb_]     = f2hb(w_ * v_.x);                            \
            imgh[hb_ + 2] = f2hb(w_ * v_.y);                            \
            imgh[hb_ + 4] = f2hb(w_);                                   \
        } }
    {
        const int4* r4 = (const int4*)(rec + beg);
        const int n2 = cnt >> 1;
        for (int t = tid; t < n2; t += 512) {
            int4 q = r4[t];
            PREC(q.x, q.y)
            PREC(q.z, q.w)
        }
        for (int t = (n2 << 1) + tid; t < cnt; t += 512) {
            int2 rc = rec[beg + t];
            PREC(rc.x, rc.y)
        }
    }
#undef PREC
    __syncthreads();
    // coalesced dump: 40960 B per window
    int4* d4 = rec2q + (size_t)wid * (CAPW / 2);
    for (int j = tid; j < CAPW / 2; j += 512) d4[j] = img4[j];
}

// -------- mega: branchless pair stream (4-deep prefetch) + MFMA --------
__global__ __launch_bounds__(512) void k_mega(
        const int* __restrict__ noff, const unsigned char* __restrict__ ngrp,
        const char* __restrict__ rec2b, const float2* __restrict__ sx,
        const float* __restrict__ W1_rel, const float* __restrict__ W1_root,
        const float* __restrict__ b1,
        const float* __restrict__ W2_rel, const float* __restrict__ b2,
        const float* __restrict__ W2_root,
        const float* __restrict__ W3_rel, const float* __restrict__ W3_root,
        float* __restrict__ p, float* __restrict__ r) {
    __shared__ _Float16 aggh[MNP * AP];       // 18432 B
    __shared__ _Float16 Bt[HID * BPITCH];     // 17408 B
    __shared__ float2 sxl[MNP];               // 1024 B -> 36.9 KB
    const int tid = threadIdx.x;
    const int f = tid & 63;
    const int wv = tid >> 6;                  // 0..7
    const int gi0 = blockIdx.x * MNP;

    for (int j = tid; j < MNP * AP / 2; j += 512) ((int*)aggh)[j] = 0;
    for (int idx = tid; idx < HID * HID; idx += 512) {
        int k = idx >> 6, n = idx & 63;
        Bt[n * BPITCH + k]       = (_Float16)W2_rel[idx];
        Bt[n * BPITCH + HID + k] = (_Float16)W2_root[idx];
    }
    if (tid < MNP) {
        int gi = gi0 + tid;
        sxl[tid] = (gi < NN) ? sx[gi] : make_float2(0.f, 0.f);
    }
    const float w1rf = W1_rel[f], w1tf = W1_root[f], b1ff = b1[f];
    __syncthreads();

    {
        const int first = gi0 + wv * 16;
        int soff = __builtin_amdgcn_readfirstlane(noff[first]);
        const int4 gvv = *(const int4*)(ngrp + first);
        unsigned ua = __builtin_amdgcn_readfirstlane((unsigned)gvv.x);
        unsigned ub = __builtin_amdgcn_readfirstlane((unsigned)gvv.y);
        unsigned uc = __builtin_amdgcn_readfirstlane((unsigned)gvv.z);
        unsigned ud = __builtin_amdgcn_readfirstlane((unsigned)gvv.w);
        unsigned long long clo = (unsigned long long)ua | ((unsigned long long)ub << 32);
        unsigned long long chi = (unsigned long long)uc | ((unsigned long long)ud << 32);
        #define BSUM(u) (((u) & 255u) + (((u) >> 8) & 255u) + (((u) >> 16) & 255u) + ((u) >> 24))
        const int tg = (int)(BSUM(ua) + BSUM(ub) + BSUM(uc) + BSUM(ud));
        #undef BSUM

        const h2v w1r2 = {(_Float16)w1rf, (_Float16)w1rf};
        const h2v w1t2 = {(_Float16)w1tf, (_Float16)w1tf};
        const h2v b1f2 = {(_Float16)b1ff, (_Float16)b1ff};
        const h2v one2 = {(_Float16)1.f, (_Float16)1.f};
        const h2v zero2 = {(_Float16)0.f, (_Float16)0.f};

        float a0 = 0.f, a1 = 0.f, a2 = 0.f, a3 = 0.f;
        int nrow = wv * 16;
        const int rowend = nrow + 16;
        int grem = (int)(clo & 255); clo = (clo >> 8) | (chi << 56); chi >>= 8;
        while (grem == 0 && nrow + 1 < rowend) {
            ++nrow; grem = (int)(clo & 255);
            clo = (clo >> 8) | (chi << 56); chi >>= 8;
        }

        const int4* rp = (const int4*)rec2b + (soff >> 1);
        int4 A0, A1, A2, A3, B0, B1, B2, B3, C0, C1, C2, C3, D0, D1, D2, D3;
        if (tg >= 1) { A0 = rp[0]; A1 = rp[1]; A2 = rp[2];  A3 = rp[3]; }
        if (tg >= 2) { B0 = rp[4]; B1 = rp[5]; B2 = rp[6];  B3 = rp[7]; }
        if (tg >= 3) { C0 = rp[8]; C1 = rp[9]; C2 = rp[10]; C3 = rp[11]; }
        rp += 12;

#define PP(Q, AA) {                                          \
        h2v z_ = ash2((unsigned)(Q).z) * b1f2;               \
        z_ = ash2((unsigned)(Q).y) * w1t2 + z_;              \
        z_ = ash2((unsigned)(Q).x) * w1r2 + z_;              \
        z_ = __builtin_elementwise_max(z_, zero2);           \
        AA = __builtin_amdgcn_fdot2(z_, one2, AA, false); }

#define BNDRY() {                                                        \
        if (--grem == 0) {                                               \
            aggh[nrow * AP + f] = (_Float16)((a0 + a1) + (a2 + a3));     \
            a0 = a1 = a2 = a3 = 0.f;                                     \
            ++nrow; grem = (int)(clo & 255);                             \
            clo = (clo >> 8) | (chi << 56); chi >>= 8;                   \
            while (grem == 0 && nrow + 1 < rowend) {                     \
                ++nrow; grem = (int)(clo & 255);                         \
                clo = (clo >> 8) | (chi << 56); chi >>= 8;               \
            }                                                            \
        } }

        int t = 0;
        // steady state: 4 groups in flight (~4x56 cyc of latency cover)
        while (t + 4 <= tg) {
            D0 = rp[0]; D1 = rp[1]; D2 = rp[2]; D3 = rp[3];
            PP(A0, a0) PP(A1, a1) PP(A2, a2) PP(A3, a3) BNDRY(); ++t;
            A0 = rp[4]; A1 = rp[5]; A2 = rp[6]; A3 = rp[7];
            PP(B0, a0) PP(B1, a1) PP(B2, a2) PP(B3, a3) BNDRY(); ++t;
            B0 = rp[8]; B1 = rp[9]; B2 = rp[10]; B3 = rp[11];
            PP(C0, a0) PP(C1, a1) PP(C2, a2) PP(C3, a3) BNDRY(); ++t;
            C0 = rp[12]; C1 = rp[13]; C2 = rp[14]; C3 = rp[15];
            PP(D0, a0) PP(D1, a1) PP(D2, a2) PP(D3, a3) BNDRY(); ++t;
            rp += 16;
        }
        if (t < tg) {
            PP(A0, a0) PP(A1, a1) PP(A2, a2) PP(A3, a3) BNDRY(); ++t;
            if (t < tg) {
                PP(B0, a0) PP(B1, a1) PP(B2, a2) PP(B3, a3) BNDRY(); ++t;
                if (t < tg) {
                    PP(C0, a0) PP(C1, a1) PP(C2, a2) PP(C3, a3) BNDRY(); ++t;
                }
            }
        }
#undef PP
#undef BNDRY
    }
    __syncthreads();

    const int m16 = tid & 15;
    const int quad = (tid & 63) >> 4;
    f32x4 acc[4];
    #pragma unroll
    for (int c_ = 0; c_ < 4; ++c_) acc[c_] = (f32x4){0.f, 0.f, 0.f, 0.f};

    const float2 sm = sxl[wv * 16 + m16];

    #pragma unroll
    for (int kt = 0; kt < 4; ++kt) {
        const int kk = kt * 32;
        half8 af;
        if (kt < 2) {
            af = *(const half8*)&aggh[(wv * 16 + m16) * AP + kk + quad * 8];
        } else {
            const int fk0 = (kt - 2) * 32 + quad * 8;
            #pragma unroll
            for (int j = 0; j < 8; ++j) {
                const float wr = W1_rel[fk0 + j], wt = W1_root[fk0 + j], bb = b1[fk0 + j];
                af[j] = (_Float16)fmaxf(0.f, fmaf(sm.x, wr, fmaf(sm.y, wt, bb)));
            }
        }
        #pragma unroll
        for (int ct = 0; ct < 4; ++ct) {
            const half8 bfrag = *(const half8*)&Bt[(ct * 16 + m16) * BPITCH + kk + quad * 8];
            acc[ct] = __builtin_amdgcn_mfma_f32_16x16x32_f16(af, bfrag, acc[ct], 0, 0, 0);
        }
    }

    float b2c[4], w3rc[4], w3tc[4];
    #pragma unroll
    for (int ct = 0; ct < 4; ++ct) {
        const int col = ct * 16 + m16;
        b2c[ct] = b2[col]; w3rc[ct] = W3_rel[col]; w3tc[ct] = W3_root[col];
    }
    float pv[4] = {0.f, 0.f, 0.f, 0.f}, rv[4] = {0.f, 0.f, 0.f, 0.f};
    #pragma unroll
    for (int ct = 0; ct < 4; ++ct) {
        #pragma unroll
        for (int reg = 0; reg < 4; ++reg) {
            const float h2_ = fmaxf(0.f, acc[ct][reg] + b2c[ct]);
            pv[reg] = fmaf(h2_, w3rc[ct], pv[reg]);
            rv[reg] = fmaf(h2_, w3tc[ct], rv[reg]);
        }
    }
    #pragma unroll
    for (int reg = 0; reg < 4; ++reg) {
        #pragma unroll
        for (int msk = 1; msk < 16; msk <<= 1) {
            pv[reg] += __shfl_xor(pv[reg], msk, 64);
            rv[reg] += __shfl_xor(rv[reg], msk, 64);
        }
    }
    if (m16 == 0) {
        #pragma unroll
        for (int reg = 0; reg < 4; ++reg) {
            const int gi = gi0 + wv * 16 + quad * 4 + reg;
            if (gi < NN) { p[gi] = pv[reg]; r[gi] = rv[reg]; }
        }
    }
}

// -------- bucketed output (unsorted rec): out = seg_sum(w * p[src]) + r + b3 --------
__global__ __launch_bounds__(512) void k_out(const int* __restrict__ gcur,
                                             const int2* __restrict__ rec,
                                             const float* __restrict__ pp,
                                             const float* __restrict__ rr,
                                             const float* __restrict__ b3,
                                             float* __restrict__ out) {
    __shared__ float loc[NPB];
    if (threadIdx.x < NPB) loc[threadIdx.x] = 0.f;
    __syncthreads();
    const int b = blockIdx.x;
    const int beg = b * CAP, cnt = gcur[b] - beg;
    for (int t = threadIdx.x; t < cnt; t += 512) {
        int2 rc = rec[beg + t];
        atomicAdd(&loc[rc.x >> 17], __int_as_float(rc.y) * pp[rc.x & SRCM]);
    }
    __syncthreads();
    int i = b * NPB + threadIdx.x;
    if (threadIdx.x < NPB && i < NN) out[i] = loc[threadIdx.x] + rr[i] + b3[0];
}

extern "C" void kernel_launch(void* const* d_in, const int* in_sizes, int n_in,
                              void* d_out, int out_size, void* d_ws, size_t ws_size,
                              hipStream_t stream) {
    const float* x       = (const float*)d_in[0];
    const int*   ei      = (const int*)  d_in[1];
    const float* ew      = (const float*)d_in[2];
    const float* W1_rel  = (const float*)d_in[3];
    const float* b1      = (const float*)d_in[4];
    const float* W1_root = (const float*)d_in[5];
    const float* W2_rel  = (const float*)d_in[6];
    const float* b2      = (const float*)d_in[7];
    const float* W2_root = (const float*)d_in[8];
    const float* W3_rel  = (const float*)d_in[9];
    const float* b3      = (const float*)d_in[10];
    const float* W3_root = (const float*)d_in[11];

    const int* src = ei;
    const int* dst = ei + NE;

    // workspace layout (~67 MB of the ~268 MB workspace)
    const size_t REC_SLOTS = (size_t)NB * CAP;            // 3.60M slots, 28.8 MB
    int2*          rec   = (int2*)d_ws;
    float2*        sx    = (float2*)(rec + REC_SLOTS);    // 800 KB
    float*         p     = (float*)(sx + NN);             // 400 KB
    float*         r     = p + NN;                        // 400 KB
    int*           noff  = (int*)(r + NN);                // NNP*4
    unsigned char* ngrp  = (unsigned char*)(noff + NNP);  // NNP
    int*           gcur  = (int*)(ngrp + NNP);            // NB*4
    unsigned char* dlb   = (unsigned char*)(gcur + NB);   // NB*CAP = 3.6 MB
    char*          tail  = (char*)(dlb + REC_SLOTS);
    size_t         off   = ((size_t)(tail - (char*)d_ws) + 15) & ~(size_t)15;
    char*          rec2  = (char*)d_ws + off;             // NMW*CAPW*8 + slack = 32.0 MB

    k_init<<<1, 512, 0, stream>>>(gcur);
    k_scatter<<<NCH, 256, 0, stream>>>(src, dst, ew, gcur, rec, dlb);
    k_s1<<<NB, 512, 0, stream>>>(gcur, rec, x, sx);
    k_pack<<<NMW, 512, 0, stream>>>(gcur, rec, dlb, sx, (int4*)rec2, noff, ngrp);
    k_mega<<<NMW, 512, 0, stream>>>(noff, ngrp, rec2, sx,
                                    W1_rel, W1_root, b1,
                                    W2_rel, b2, W2_root,
                                    W3_rel, W3_root, p, r);
    k_out<<<NB, 512, 0, stream>>>(gcur, rec, p, r, b3, (float*)d_out);
}